// Round 2
// baseline (10442.979 us; speedup 1.0000x reference)
//
#include <hip/hip_runtime.h>
#include <hip/hip_bf16.h>

// Model constants
#define TT 512
#define NN 1024
#define NH 16
#define HD 64
#define NL 12
#define VV 50257

__device__ __forceinline__ float gelu_f(float x) {
    // jax.nn.gelu approximate=True (tanh form)
    float x3 = x * x * x;
    return 0.5f * x * (1.0f + tanhf(0.7978845608028654f * (x + 0.044715f * x3)));
}

// x[row, :] = 1024*emb[tok[row], :] + 32*pos[t, :]
__global__ __launch_bounds__(256) void embed_k(const int* __restrict__ tok,
        const float* __restrict__ emb, const float* __restrict__ pos,
        float* __restrict__ x) {
    int row = blockIdx.x;
    int t = row & (TT - 1);
    int tk = tok[row];
    int c = threadIdx.x * 4;
    float4 e = *reinterpret_cast<const float4*>(emb + (size_t)tk * NN + c);
    float4 p = *reinterpret_cast<const float4*>(pos + (size_t)t * NN + c);
    float4 o;
    o.x = 1024.f * e.x + 32.f * p.x;
    o.y = 1024.f * e.y + 32.f * p.y;
    o.z = 1024.f * e.z + 32.f * p.z;
    o.w = 1024.f * e.w + 32.f * p.w;
    *reinterpret_cast<float4*>(x + (size_t)row * NN + c) = o;
}

// Row LayerNorm over N=1024 (+ optional gelu)
template<int ACT>
__global__ __launch_bounds__(256) void ln_k(const float* __restrict__ in,
        float* __restrict__ out, const float* __restrict__ sc, const float* __restrict__ bi) {
    int row = blockIdx.x;
    const float* r = in + (size_t)row * NN;
    int tid = threadIdx.x;
    float v[4]; float s1 = 0.f, s2 = 0.f;
    #pragma unroll
    for (int i = 0; i < 4; ++i) { v[i] = r[tid + i * 256]; s1 += v[i]; s2 += v[i] * v[i]; }
    #pragma unroll
    for (int off = 32; off > 0; off >>= 1) { s1 += __shfl_xor(s1, off); s2 += __shfl_xor(s2, off); }
    __shared__ float red[8];
    __shared__ float st[2];
    int wid = tid >> 6;
    if ((tid & 63) == 0) { red[wid] = s1; red[4 + wid] = s2; }
    __syncthreads();
    if (tid == 0) {
        float a = red[0] + red[1] + red[2] + red[3];
        float b = red[4] + red[5] + red[6] + red[7];
        float mu = a * (1.f / NN);
        float var = b * (1.f / NN) - mu * mu;
        st[0] = mu; st[1] = rsqrtf(var + 1e-6f);
    }
    __syncthreads();
    float mu = st[0], rs = st[1];
    float* o = out + (size_t)row * NN;
    #pragma unroll
    for (int i = 0; i < 4; ++i) {
        int c = tid + i * 256;
        float y = (v[i] - mu) * rs * sc[c] + bi[c];
        if (ACT) y = gelu_f(y);
        o[c] = y;
    }
}

// qk buffer [B*T, 2048] -> per-head LN -> qh/kh [B,H,T,64]
__global__ __launch_bounds__(256) void headln_k(const float* __restrict__ qk,
        const float* __restrict__ qs, const float* __restrict__ qb,
        const float* __restrict__ ks, const float* __restrict__ kb,
        float* __restrict__ qh, float* __restrict__ kh) {
    int u = blockIdx.x * 4 + (threadIdx.x >> 6);
    int lane = threadIdx.x & 63;
    int h = u & 15;
    int s = (u >> 4) & 1;
    int t = (u >> 5) & (TT - 1);
    int b = u >> 14;
    float x = qk[(size_t)(b * TT + t) * 2048 + h * 128 + s * 64 + lane];
    float s1 = x, s2 = x * x;
    #pragma unroll
    for (int off = 32; off > 0; off >>= 1) { s1 += __shfl_xor(s1, off); s2 += __shfl_xor(s2, off); }
    float mu = s1 * (1.f / 64.f);
    float var = s2 * (1.f / 64.f) - mu * mu;
    float rs = rsqrtf(var + 1e-6f);
    const float* scp = s ? ks : qs;
    const float* bip = s ? kb : qb;
    float y = (x - mu) * rs * scp[lane] + bip[lane];
    float* dst = s ? kh : qh;
    dst[((size_t)(b * NH + h) * TT + t) * HD + lane] = y;
}

// Generic f32 GEMM: C[M,Nn] = epilogue(A[M,K] @ f32 W[K,Nn])
// ACT: gelu(scale*acc); RES: resid + rbeta*scale*acc; OUTB: (acc+bias)*scale
template<int ACT, int RES, int OUTB>
__global__ __launch_bounds__(256) void gemm_k(const float* __restrict__ A,
        const float* __restrict__ W, float* __restrict__ Cout,
        const float* __restrict__ bias, const float* __restrict__ resid,
        float scale, float rbeta, int M, int K, int Nn) {
    __shared__ float As[64][17];
    __shared__ float Bs[16][64];
    int tid = threadIdx.x;
    int n0 = blockIdx.x * 64;
    int m0 = blockIdx.y * 64;
    int ty = tid >> 4, tx = tid & 15;
    float c[4][4] = {};
    for (int k0 = 0; k0 < K; k0 += 16) {
        #pragma unroll
        for (int j = 0; j < 4; ++j) {
            int e = tid + j * 256;
            As[e >> 4][e & 15] = A[(size_t)(m0 + (e >> 4)) * K + k0 + (e & 15)];
        }
        #pragma unroll
        for (int j = 0; j < 4; ++j) {
            int e = tid + j * 256;
            int kr = e >> 6, nc = e & 63;
            int n = n0 + nc;
            Bs[kr][nc] = (n < Nn) ? W[(size_t)(k0 + kr) * Nn + n] : 0.f;
        }
        __syncthreads();
        #pragma unroll
        for (int kk = 0; kk < 16; ++kk) {
            float4 bv = *reinterpret_cast<const float4*>(&Bs[kk][tx * 4]);
            #pragma unroll
            for (int i = 0; i < 4; ++i) {
                float av = As[ty * 4 + i][kk];
                c[i][0] += av * bv.x; c[i][1] += av * bv.y;
                c[i][2] += av * bv.z; c[i][3] += av * bv.w;
            }
        }
        __syncthreads();
    }
    #pragma unroll
    for (int i = 0; i < 4; ++i) {
        int m = m0 + ty * 4 + i;
        #pragma unroll
        for (int j = 0; j < 4; ++j) {
            int n = n0 + tx * 4 + j;
            if (n < Nn) {
                if (OUTB) {
                    Cout[(size_t)m * Nn + n] = (c[i][j] + bias[n]) * scale;
                } else {
                    float val = c[i][j] * scale;
                    if (ACT) val = gelu_f(val);
                    if (RES) val = resid[(size_t)m * Nn + n] + rbeta * val;
                    Cout[(size_t)m * Nn + n] = val;
                }
            }
        }
    }
}

// A[bh,q,k] = exp(q·k/64) for k<=q else 0   (tile 64x64)
__global__ __launch_bounds__(256) void scores_k(const float* __restrict__ qh,
        const float* __restrict__ kh, float* __restrict__ Ab) {
    int kt = blockIdx.x, qt = blockIdx.y, bh = blockIdx.z;
    float* At = Ab + (size_t)bh * TT * TT;
    int tid = threadIdx.x, ty = tid >> 4, tx = tid & 15;
    if (kt > qt) {
        #pragma unroll
        for (int i = 0; i < 4; ++i)
            #pragma unroll
            for (int j = 0; j < 4; ++j)
                At[(size_t)(qt * 64 + ty * 4 + i) * TT + kt * 64 + tx * 4 + j] = 0.f;
        return;
    }
    __shared__ float qs[64][68];
    __shared__ float ks[64][68];
    const float* qp = qh + (size_t)bh * TT * HD;
    const float* kp = kh + (size_t)bh * TT * HD;
    #pragma unroll
    for (int j = 0; j < 16; ++j) {
        int e = tid + j * 256;
        int r = e >> 6, cc = e & 63;
        qs[r][cc] = qp[(size_t)(qt * 64 + r) * HD + cc];
        ks[r][cc] = kp[(size_t)(kt * 64 + r) * HD + cc];
    }
    __syncthreads();
    float c[4][4] = {};
    #pragma unroll 4
    for (int kk = 0; kk < 64; ++kk) {
        float a[4], bb[4];
        #pragma unroll
        for (int i = 0; i < 4; ++i) a[i] = qs[ty * 4 + i][kk];
        #pragma unroll
        for (int j = 0; j < 4; ++j) bb[j] = ks[tx * 4 + j][kk];
        #pragma unroll
        for (int i = 0; i < 4; ++i)
            #pragma unroll
            for (int j = 0; j < 4; ++j)
                c[i][j] += a[i] * bb[j];
    }
    #pragma unroll
    for (int i = 0; i < 4; ++i) {
        int q = qt * 64 + ty * 4 + i;
        #pragma unroll
        for (int j = 0; j < 4; ++j) {
            int k = kt * 64 + tx * 4 + j;
            At[(size_t)q * TT + k] = (k <= q) ? expf(c[i][j] * (1.f / 64.f)) : 0.f;
        }
    }
}

// phi = exp_A / rowsum, in place
__global__ __launch_bounds__(128) void rownorm_k(float* __restrict__ Ab) {
    float* r = Ab + (size_t)blockIdx.x * TT;
    int tid = threadIdx.x;
    float v[4]; float s = 0.f;
    #pragma unroll
    for (int i = 0; i < 4; ++i) { v[i] = r[tid + i * 128]; s += v[i]; }
    #pragma unroll
    for (int off = 32; off > 0; off >>= 1) s += __shfl_xor(s, off);
    __shared__ float red[2];
    if ((tid & 63) == 0) red[tid >> 6] = s;
    __syncthreads();
    float inv = 1.f / (red[0] + red[1]);
    #pragma unroll
    for (int i = 0; i < 4; ++i) r[tid + i * 128] = v[i] * inv;
}

// o[b, q, h*64+d] = sum_k phi[bh,q,k] * v[b,k,h*64+d]
__global__ __launch_bounds__(256) void pv_k(const float* __restrict__ Ab,
        const float* __restrict__ vb, float* __restrict__ ob) {
    int qt = blockIdx.x, bh = blockIdx.y;
    int b = bh >> 4, hh = bh & 15;
    const float* At = Ab + (size_t)bh * TT * TT;
    __shared__ float ps[64][68];
    __shared__ float vs[64][68];
    int tid = threadIdx.x, ty = tid >> 4, tx = tid & 15;
    float c[4][4] = {};
    for (int kt = 0; kt <= qt; ++kt) {
        #pragma unroll
        for (int j = 0; j < 16; ++j) {
            int e = tid + j * 256;
            int r = e >> 6, cc = e & 63;
            ps[r][cc] = At[(size_t)(qt * 64 + r) * TT + kt * 64 + cc];
            vs[r][cc] = vb[(size_t)(b * TT + kt * 64 + r) * NN + hh * 64 + cc];
        }
        __syncthreads();
        #pragma unroll 4
        for (int kk = 0; kk < 64; ++kk) {
            float4 bv = *reinterpret_cast<const float4*>(&vs[kk][tx * 4]);
            #pragma unroll
            for (int i = 0; i < 4; ++i) {
                float av = ps[ty * 4 + i][kk];
                c[i][0] += av * bv.x; c[i][1] += av * bv.y;
                c[i][2] += av * bv.z; c[i][3] += av * bv.w;
            }
        }
        __syncthreads();
    }
    #pragma unroll
    for (int i = 0; i < 4; ++i)
        #pragma unroll
        for (int j = 0; j < 4; ++j)
            ob[(size_t)(b * TT + qt * 64 + ty * 4 + i) * NN + hh * 64 + tx * 4 + j] = c[i][j];
}

extern "C" void kernel_launch(void* const* d_in, const int* in_sizes, int n_in,
                              void* d_out, int out_size, void* d_ws, size_t ws_size,
                              hipStream_t stream) {
    (void)in_sizes; (void)n_in; (void)out_size; (void)ws_size;
    const int*   tok  = (const int*)d_in[0];
    const float* emb  = (const float*)d_in[1];
    const float* pos  = (const float*)d_in[2];
    const float* ln1s = (const float*)d_in[3];
    const float* ln1b = (const float*)d_in[4];
    const float* qkW  = (const float*)d_in[5];
    const float* vW   = (const float*)d_in[6];
    const float* oW   = (const float*)d_in[7];
    const float* qns  = (const float*)d_in[8];
    const float* qnb  = (const float*)d_in[9];
    const float* kns  = (const float*)d_in[10];
    const float* knb  = (const float*)d_in[11];
    const float* ln2s = (const float*)d_in[12];
    const float* ln2b = (const float*)d_in[13];
    const float* W1   = (const float*)d_in[14];
    const float* W2   = (const float*)d_in[15];
    const float* lnfs = (const float*)d_in[16];
    const float* lnfb = (const float*)d_in[17];
    const float* outW = (const float*)d_in[18];
    const float* outb = (const float*)d_in[19];
    float* out = (float*)d_out;

    // ws layout (floats): x(1M) h(1M) mq(2M: qk buf / mlp mid) qh(1M) kh(1M)
    //                     vb(1M) ob(1M) Ab(8M)  => ~66 MB total
    float* ws = (float*)d_ws;
    const size_t M1 = 1u << 20;
    float* x  = ws;
    float* h  = x + M1;
    float* mq = h + M1;
    float* qh = mq + 2 * M1;
    float* kh = qh + M1;
    float* vb = kh + M1;
    float* ob = vb + M1;
    float* Ab = ob + M1;

    const float inv32 = 0.03125f;       // 1/sqrt(N)
    const float betaD = 1.f / 12.f;     // BETA / D

    embed_k<<<1024, 256, 0, stream>>>(tok, emb, pos, x);
    for (int l = 0; l < NL; ++l) {
        ln_k<1><<<1024, 256, 0, stream>>>(x, h, ln1s + l * NN, ln1b + l * NN);
        gemm_k<0,0,0><<<dim3(32, 16), 256, 0, stream>>>(h, qkW + (size_t)l * NN * 2048, mq,
                nullptr, nullptr, inv32, 0.f, 1024, NN, 2048);
        headln_k<<<8192, 256, 0, stream>>>(mq, qns + l * HD, qnb + l * HD,
                kns + l * HD, knb + l * HD, qh, kh);
        gemm_k<0,0,0><<<dim3(16, 16), 256, 0, stream>>>(h, vW + (size_t)l * NN * NN, vb,
                nullptr, nullptr, inv32, 0.f, 1024, NN, NN);
        scores_k<<<dim3(8, 8, 32), 256, 0, stream>>>(qh, kh, Ab);
        rownorm_k<<<16384, 128, 0, stream>>>(Ab);
        pv_k<<<dim3(8, 32), 256, 0, stream>>>(Ab, vb, ob);
        gemm_k<0,1,0><<<dim3(16, 16), 256, 0, stream>>>(ob, oW + (size_t)l * NN * NN, x,
                nullptr, x, inv32, betaD, 1024, NN, NN);
        ln_k<1><<<1024, 256, 0, stream>>>(x, h, ln2s + l * NN, ln2b + l * NN);
        gemm_k<1,0,0><<<dim3(16, 16), 256, 0, stream>>>(h, W1 + (size_t)l * NN * NN, mq,
                nullptr, nullptr, inv32, 0.f, 1024, NN, NN);
        gemm_k<0,1,0><<<dim3(16, 16), 256, 0, stream>>>(mq, W2 + (size_t)l * NN * NN, x,
                nullptr, x, inv32, betaD, 1024, NN, NN);
    }
    ln_k<0><<<1024, 256, 0, stream>>>(x, h, lnfs, lnfb);
    gemm_k<0,0,1><<<dim3((VV + 63) / 64, 16), 256, 0, stream>>>(h, outW, out,
            outb, nullptr, inv32, 0.f, 1024, NN, VV);
}

// Round 3
// 3886.553 us; speedup vs baseline: 2.6870x; 2.6870x over previous
//
#include <hip/hip_runtime.h>
#include <hip/hip_bf16.h>

// Model constants
#define TT 512
#define NN 1024
#define NH 16
#define HD 64
#define NL 12
#define VV 50257

typedef unsigned short u16;
typedef short bf16x8 __attribute__((ext_vector_type(8)));
typedef float f32x4 __attribute__((ext_vector_type(4)));

__device__ __forceinline__ float gelu_f(float x) {
    float x3 = x * x * x;
    return 0.5f * x * (1.0f + tanhf(0.7978845608028654f * (x + 0.044715f * x3)));
}

// fp32 -> bf16 RNE (finite inputs only)
__device__ __forceinline__ u16 f2b(float f) {
    unsigned int u = __float_as_uint(f);
    return (u16)((u + 0x7FFFu + ((u >> 16) & 1u)) >> 16);
}

// async global->LDS, 16B per lane; LDS dest is wave-uniform base + lane*16
__device__ __forceinline__ void gload16(const void* g, void* l) {
    __builtin_amdgcn_global_load_lds(
        (const __attribute__((address_space(1))) unsigned int*)g,
        (__attribute__((address_space(3))) unsigned int*)l,
        16, 0, 0);
}

// x[row,:] = 1024*emb[tok[row],:] + 32*pos[t,:]
__global__ __launch_bounds__(256) void embed_k(const int* __restrict__ tok,
        const float* __restrict__ emb, const float* __restrict__ pos,
        float* __restrict__ x) {
    int row = blockIdx.x;
    int t = row & (TT - 1);
    int tk = tok[row];
    int c = threadIdx.x * 4;
    float4 e = *reinterpret_cast<const float4*>(emb + (size_t)tk * NN + c);
    float4 p = *reinterpret_cast<const float4*>(pos + (size_t)t * NN + c);
    float4 o;
    o.x = 1024.f * e.x + 32.f * p.x;
    o.y = 1024.f * e.y + 32.f * p.y;
    o.z = 1024.f * e.z + 32.f * p.z;
    o.w = 1024.f * e.w + 32.f * p.w;
    *reinterpret_cast<float4*>(x + (size_t)row * NN + c) = o;
}

// Row LayerNorm over N=1024 (+ optional gelu), bf16 output
template<int ACT>
__global__ __launch_bounds__(256) void ln_k(const float* __restrict__ in,
        u16* __restrict__ out, const float* __restrict__ sc, const float* __restrict__ bi) {
    int row = blockIdx.x;
    const float* r = in + (size_t)row * NN;
    int tid = threadIdx.x;
    float v[4]; float s1 = 0.f, s2 = 0.f;
    #pragma unroll
    for (int i = 0; i < 4; ++i) { v[i] = r[tid + i * 256]; s1 += v[i]; s2 += v[i] * v[i]; }
    #pragma unroll
    for (int off = 32; off > 0; off >>= 1) { s1 += __shfl_xor(s1, off); s2 += __shfl_xor(s2, off); }
    __shared__ float red[8];
    __shared__ float st[2];
    int wid = tid >> 6;
    if ((tid & 63) == 0) { red[wid] = s1; red[4 + wid] = s2; }
    __syncthreads();
    if (tid == 0) {
        float a = red[0] + red[1] + red[2] + red[3];
        float b = red[4] + red[5] + red[6] + red[7];
        float mu = a * (1.f / NN);
        float var = b * (1.f / NN) - mu * mu;
        st[0] = mu; st[1] = rsqrtf(var + 1e-6f);
    }
    __syncthreads();
    float mu = st[0], rs = st[1];
    u16* o = out + (size_t)row * NN;
    #pragma unroll
    for (int i = 0; i < 4; ++i) {
        int c = tid + i * 256;
        float y = (v[i] - mu) * rs * sc[c] + bi[c];
        if (ACT) y = gelu_f(y);
        o[c] = f2b(y);
    }
}

// qk buffer [B*T, 2048] -> per-head LN -> qh/kh [B,H,T,64] fp32
__global__ __launch_bounds__(256) void headln_k(const float* __restrict__ qk,
        const float* __restrict__ qs, const float* __restrict__ qb,
        const float* __restrict__ ks, const float* __restrict__ kb,
        float* __restrict__ qh, float* __restrict__ kh) {
    int u = blockIdx.x * 4 + (threadIdx.x >> 6);
    int lane = threadIdx.x & 63;
    int h = u & 15;
    int s = (u >> 4) & 1;
    int t = (u >> 5) & (TT - 1);
    int b = u >> 14;
    float x = qk[(size_t)(b * TT + t) * 2048 + h * 128 + s * 64 + lane];
    float s1 = x, s2 = x * x;
    #pragma unroll
    for (int off = 32; off > 0; off >>= 1) { s1 += __shfl_xor(s1, off); s2 += __shfl_xor(s2, off); }
    float mu = s1 * (1.f / 64.f);
    float var = s2 * (1.f / 64.f) - mu * mu;
    float rs = rsqrtf(var + 1e-6f);
    const float* scp = s ? ks : qs;
    const float* bip = s ? kb : qb;
    float y = (x - mu) * rs * scp[lane] + bip[lane];
    float* dst = s ? kh : qh;
    dst[((size_t)(b * NH + h) * TT + t) * HD + lane] = y;
}

// W fp32 [K][Ncols] (ld=ldW) -> Wt bf16 [Npad][K] (k-contiguous); pads with 0
__global__ __launch_bounds__(256) void transpose_k(const float* __restrict__ W,
        u16* __restrict__ Wt, int Ncols, int ldW, int K) {
    __shared__ float t[64][65];
    int n0 = blockIdx.x * 64, k0 = blockIdx.y * 64;
    int tid = threadIdx.x;
    #pragma unroll
    for (int j = 0; j < 4; ++j) {
        int e = tid + j * 256;
        int kr = e >> 4, nc = (e & 15) * 4;
        int n = n0 + nc;
        float4 v = {0.f, 0.f, 0.f, 0.f};
        if (n + 3 < Ncols) {
            v = *reinterpret_cast<const float4*>(W + (size_t)(k0 + kr) * ldW + n);
        } else {
            if (n + 0 < Ncols) v.x = W[(size_t)(k0 + kr) * ldW + n + 0];
            if (n + 1 < Ncols) v.y = W[(size_t)(k0 + kr) * ldW + n + 1];
            if (n + 2 < Ncols) v.z = W[(size_t)(k0 + kr) * ldW + n + 2];
            if (n + 3 < Ncols) v.w = W[(size_t)(k0 + kr) * ldW + n + 3];
        }
        t[kr][nc + 0] = v.x; t[kr][nc + 1] = v.y; t[kr][nc + 2] = v.z; t[kr][nc + 3] = v.w;
    }
    __syncthreads();
    #pragma unroll
    for (int j = 0; j < 4; ++j) {
        int e = tid + j * 256;
        int nr = e >> 4, kc = (e & 15) * 4;
        ushort4 o;
        o.x = f2b(t[kc + 0][nr]);
        o.y = f2b(t[kc + 1][nr]);
        o.z = f2b(t[kc + 2][nr]);
        o.w = f2b(t[kc + 3][nr]);
        *reinterpret_cast<ushort4*>(Wt + (size_t)(n0 + nr) * K + k0 + kc) = o;
    }
}

// swizzled LDS fragment read: row r, logical 16B chunk c
__device__ __forceinline__ bf16x8 ldsfrag(const u16* base, int r, int c) {
    int off = r * 64 + ((c ^ (r & 7)) << 3);
    return *reinterpret_cast<const bf16x8*>(base + off);
}

// MFMA GEMM: C = epilogue(A[M][K]bf16 @ Bt[N][K]bf16^T), 128x128 tile, BK=64.
// EPI 0: fp32 C = acc*scale
// EPI 1: fp32 C = C + rbeta*(acc*scale)   (residual in place)
// EPI 2: bf16 C = gelu(acc*scale)
// EPI 3: fp32 C[row*ldC + coff+n] = (acc + bias[coff+n])*scale, guarded coff+n<cmax
template<int EPI>
__global__ __launch_bounds__(256) void mgemm_k(const u16* __restrict__ A,
        const u16* __restrict__ Bt, void* __restrict__ C,
        const float* __restrict__ bias, int K, int ldC, int coff, int cmax,
        float scale, float rbeta) {
    __shared__ __align__(16) u16 As[128 * 64];
    __shared__ __align__(16) u16 Bs[128 * 64];
    int tid = threadIdx.x;
    int lam = tid & 63;
    int w = tid >> 6;
    int m0 = blockIdx.y * 128, n0 = blockIdx.x * 128;
    int lr = lam >> 3;              // row-in-8 within a 1KB issue
    int lc = (lam & 7) ^ lr;        // inverse-swizzled logical chunk for this lane
    const u16* Abase = A + (size_t)m0 * K;
    const u16* Bbase = Bt + (size_t)n0 * K;
    f32x4 acc[4][4];
    #pragma unroll
    for (int i = 0; i < 4; ++i)
        #pragma unroll
        for (int j = 0; j < 4; ++j) acc[i][j] = (f32x4)0.0f;
    int wr = (w >> 1) * 64, wc = (w & 1) * 64;
    int fr = lam & 15, fg = lam >> 4;       // fragment row, k-group
    for (int k0 = 0; k0 < K; k0 += 64) {
        #pragma unroll
        for (int i = 0; i < 4; ++i) {
            int q = w * 4 + i;              // 16 issues cover 128 rows (8 rows each)
            int r = q * 8 + lr;
            gload16(Abase + (size_t)r * K + k0 + lc * 8, (char*)As + q * 1024);
            gload16(Bbase + (size_t)r * K + k0 + lc * 8, (char*)Bs + q * 1024);
        }
        __syncthreads();
        #pragma unroll
        for (int s = 0; s < 2; ++s) {       // two k=32 slices
            bf16x8 af[4], bfv[4];
            #pragma unroll
            for (int m = 0; m < 4; ++m) af[m] = ldsfrag(As, wr + m * 16 + fr, s * 4 + fg);
            #pragma unroll
            for (int n = 0; n < 4; ++n) bfv[n] = ldsfrag(Bs, wc + n * 16 + fr, s * 4 + fg);
            #pragma unroll
            for (int m = 0; m < 4; ++m)
                #pragma unroll
                for (int n = 0; n < 4; ++n)
                    acc[m][n] = __builtin_amdgcn_mfma_f32_16x16x32_bf16(af[m], bfv[n], acc[m][n], 0, 0, 0);
        }
        __syncthreads();
    }
    // C/D layout: col = lane&15, row = (lane>>4)*4 + reg  [m89-verified]
    #pragma unroll
    for (int m = 0; m < 4; ++m) {
        #pragma unroll
        for (int n = 0; n < 4; ++n) {
            int ncol = n0 + wc + n * 16 + fr;
            int mrow = m0 + wr + m * 16 + 4 * fg;
            #pragma unroll
            for (int reg = 0; reg < 4; ++reg) {
                int row = mrow + reg;
                float v = acc[m][n][reg];
                if (EPI == 0) {
                    ((float*)C)[(size_t)row * ldC + ncol] = v * scale;
                } else if (EPI == 1) {
                    float* p = (float*)C + (size_t)row * ldC + ncol;
                    *p = *p + rbeta * (v * scale);
                } else if (EPI == 2) {
                    ((u16*)C)[(size_t)row * ldC + ncol] = f2b(gelu_f(v * scale));
                } else {
                    int gc = coff + ncol;
                    if (gc < cmax)
                        ((float*)C)[(size_t)row * ldC + gc] = (v + bias[gc]) * scale;
                }
            }
        }
    }
}

// A[bh,q,k] = exp(q·k/64) for k<=q else 0   (tile 64x64, fp32)
__global__ __launch_bounds__(256) void scores_k(const float* __restrict__ qh,
        const float* __restrict__ kh, float* __restrict__ Ab) {
    int kt = blockIdx.x, qt = blockIdx.y, bh = blockIdx.z;
    float* At = Ab + (size_t)bh * TT * TT;
    int tid = threadIdx.x, ty = tid >> 4, tx = tid & 15;
    if (kt > qt) {
        #pragma unroll
        for (int i = 0; i < 4; ++i)
            #pragma unroll
            for (int j = 0; j < 4; ++j)
                At[(size_t)(qt * 64 + ty * 4 + i) * TT + kt * 64 + tx * 4 + j] = 0.f;
        return;
    }
    __shared__ float qs[64][68];
    __shared__ float ks[64][68];
    const float* qp = qh + (size_t)bh * TT * HD;
    const float* kp = kh + (size_t)bh * TT * HD;
    #pragma unroll
    for (int j = 0; j < 16; ++j) {
        int e = tid + j * 256;
        int r = e >> 6, cc = e & 63;
        qs[r][cc] = qp[(size_t)(qt * 64 + r) * HD + cc];
        ks[r][cc] = kp[(size_t)(kt * 64 + r) * HD + cc];
    }
    __syncthreads();
    float c[4][4] = {};
    #pragma unroll 4
    for (int kk = 0; kk < 64; ++kk) {
        float a[4], bb[4];
        #pragma unroll
        for (int i = 0; i < 4; ++i) a[i] = qs[ty * 4 + i][kk];
        #pragma unroll
        for (int j = 0; j < 4; ++j) bb[j] = ks[tx * 4 + j][kk];
        #pragma unroll
        for (int i = 0; i < 4; ++i)
            #pragma unroll
            for (int j = 0; j < 4; ++j)
                c[i][j] += a[i] * bb[j];
    }
    #pragma unroll
    for (int i = 0; i < 4; ++i) {
        int q = qt * 64 + ty * 4 + i;
        #pragma unroll
        for (int j = 0; j < 4; ++j) {
            int k = kt * 64 + tx * 4 + j;
            At[(size_t)q * TT + k] = (k <= q) ? expf(c[i][j] * (1.f / 64.f)) : 0.f;
        }
    }
}

// phi = exp_A / rowsum, in place
__global__ __launch_bounds__(128) void rownorm_k(float* __restrict__ Ab) {
    float* r = Ab + (size_t)blockIdx.x * TT;
    int tid = threadIdx.x;
    float v[4]; float s = 0.f;
    #pragma unroll
    for (int i = 0; i < 4; ++i) { v[i] = r[tid + i * 128]; s += v[i]; }
    #pragma unroll
    for (int off = 32; off > 0; off >>= 1) s += __shfl_xor(s, off);
    __shared__ float red[2];
    if ((tid & 63) == 0) red[tid >> 6] = s;
    __syncthreads();
    float inv = 1.f / (red[0] + red[1]);
    #pragma unroll
    for (int i = 0; i < 4; ++i) r[tid + i * 128] = v[i] * inv;
}

// o[b,q,h*64+d] = sum_k phi[bh,q,k] * v[b,k,h*64+d]; bf16 output
__global__ __launch_bounds__(256) void pv_k(const float* __restrict__ Ab,
        const float* __restrict__ vb, u16* __restrict__ ob) {
    int qt = blockIdx.x, bh = blockIdx.y;
    int b = bh >> 4, hh = bh & 15;
    const float* At = Ab + (size_t)bh * TT * TT;
    __shared__ float ps[64][68];
    __shared__ float vs[64][68];
    int tid = threadIdx.x, ty = tid >> 4, tx = tid & 15;
    float c[4][4] = {};
    for (int kt = 0; kt <= qt; ++kt) {
        #pragma unroll
        for (int j = 0; j < 16; ++j) {
            int e = tid + j * 256;
            int r = e >> 6, cc = e & 63;
            ps[r][cc] = At[(size_t)(qt * 64 + r) * TT + kt * 64 + cc];
            vs[r][cc] = vb[(size_t)(b * TT + kt * 64 + r) * NN + hh * 64 + cc];
        }
        __syncthreads();
        #pragma unroll 4
        for (int kk = 0; kk < 64; ++kk) {
            float4 bv = *reinterpret_cast<const float4*>(&vs[kk][tx * 4]);
            #pragma unroll
            for (int i = 0; i < 4; ++i) {
                float av = ps[ty * 4 + i][kk];
                c[i][0] += av * bv.x; c[i][1] += av * bv.y;
                c[i][2] += av * bv.z; c[i][3] += av * bv.w;
            }
        }
        __syncthreads();
    }
    #pragma unroll
    for (int i = 0; i < 4; ++i)
        #pragma unroll
        for (int j = 0; j < 4; ++j)
            ob[(size_t)(b * TT + qt * 64 + ty * 4 + i) * NN + hh * 64 + tx * 4 + j] = f2b(c[i][j]);
}

extern "C" void kernel_launch(void* const* d_in, const int* in_sizes, int n_in,
                              void* d_out, int out_size, void* d_ws, size_t ws_size,
                              hipStream_t stream) {
    (void)in_sizes; (void)n_in; (void)out_size; (void)ws_size;
    const int*   tok  = (const int*)d_in[0];
    const float* emb  = (const float*)d_in[1];
    const float* pos  = (const float*)d_in[2];
    const float* ln1s = (const float*)d_in[3];
    const float* ln1b = (const float*)d_in[4];
    const float* qkW  = (const float*)d_in[5];
    const float* vW   = (const float*)d_in[6];
    const float* oW   = (const float*)d_in[7];
    const float* qns  = (const float*)d_in[8];
    const float* qnb  = (const float*)d_in[9];
    const float* kns  = (const float*)d_in[10];
    const float* knb  = (const float*)d_in[11];
    const float* ln2s = (const float*)d_in[12];
    const float* ln2b = (const float*)d_in[13];
    const float* W1   = (const float*)d_in[14];
    const float* W2   = (const float*)d_in[15];
    const float* lnfs = (const float*)d_in[16];
    const float* lnfb = (const float*)d_in[17];
    const float* outW = (const float*)d_in[18];
    const float* outb = (const float*)d_in[19];
    float* out = (float*)d_out;

    // ws layout (bytes): x f32 4MB | h bf16 2MB | qkbuf f32 8MB (reused as mid bf16)
    //                    qh,kh,vb f32 12MB | ob bf16 2MB | Ab f32 32MB (reused: logits Wt)
    //                    Wt bf16 4MB   => 64MB total
    char* p = (char*)d_ws;
    float* x     = (float*)p;               p += (size_t)4  << 20;
    u16*   h     = (u16*)p;                 p += (size_t)2  << 20;
    float* qkbuf = (float*)p;               u16* mid = (u16*)qkbuf;
                                            p += (size_t)8  << 20;
    float* qh    = (float*)p;               p += (size_t)4  << 20;
    float* kh    = (float*)p;               p += (size_t)4  << 20;
    float* vb    = (float*)p;               p += (size_t)4  << 20;
    u16*   ob    = (u16*)p;                 p += (size_t)2  << 20;
    float* Ab    = (float*)p;               u16* WtL = (u16*)Ab;
                                            p += (size_t)32 << 20;
    u16*   Wt    = (u16*)p;

    const float inv32 = 0.03125f;       // 1/sqrt(N)
    const float betaD = 1.f / 12.f;     // BETA / D

    embed_k<<<1024, 256, 0, stream>>>(tok, emb, pos, x);
    for (int l = 0; l < NL; ++l) {
        ln_k<1><<<1024, 256, 0, stream>>>(x, h, ln1s + l * NN, ln1b + l * NN);
        // QK projection
        transpose_k<<<dim3(32, 16), 256, 0, stream>>>(qkW + (size_t)l * NN * 2048, Wt, 2048, 2048, NN);
        mgemm_k<0><<<dim3(16, 8), 256, 0, stream>>>(h, Wt, qkbuf, nullptr, NN, 2048, 0, 0, inv32, 0.f);
        headln_k<<<8192, 256, 0, stream>>>(qkbuf, qns + l * HD, qnb + l * HD,
                kns + l * HD, knb + l * HD, qh, kh);
        // V projection
        transpose_k<<<dim3(16, 16), 256, 0, stream>>>(vW + (size_t)l * NN * NN, Wt, NN, NN, NN);
        mgemm_k<0><<<dim3(8, 8), 256, 0, stream>>>(h, Wt, vb, nullptr, NN, NN, 0, 0, inv32, 0.f);
        // Attention (fp32 core)
        scores_k<<<dim3(8, 8, 32), 256, 0, stream>>>(qh, kh, Ab);
        rownorm_k<<<16384, 128, 0, stream>>>(Ab);
        pv_k<<<dim3(8, 32), 256, 0, stream>>>(Ab, vb, ob);
        // Output projection + residual
        transpose_k<<<dim3(16, 16), 256, 0, stream>>>(oW + (size_t)l * NN * NN, Wt, NN, NN, NN);
        mgemm_k<1><<<dim3(8, 8), 256, 0, stream>>>(ob, Wt, x, nullptr, NN, NN, 0, 0, inv32, betaD);
        // MLP
        ln_k<1><<<1024, 256, 0, stream>>>(x, h, ln2s + l * NN, ln2b + l * NN);
        transpose_k<<<dim3(16, 16), 256, 0, stream>>>(W1 + (size_t)l * NN * NN, Wt, NN, NN, NN);
        mgemm_k<2><<<dim3(8, 8), 256, 0, stream>>>(h, Wt, mid, nullptr, NN, NN, 0, 0, inv32, 0.f);
        transpose_k<<<dim3(16, 16), 256, 0, stream>>>(W2 + (size_t)l * NN * NN, Wt, NN, NN, NN);
        mgemm_k<1><<<dim3(8, 8), 256, 0, stream>>>(mid, Wt, x, nullptr, NN, NN, 0, 0, inv32, betaD);
    }
    ln_k<0><<<1024, 256, 0, stream>>>(x, h, lnfs, lnfb);
    // Logits, chunked over vocab; Wt chunk lives in the (now free) Ab region
    for (int c0 = 0; c0 < VV; c0 += 8192) {
        int cn = VV - c0; if (cn > 8192) cn = 8192;
        int npad = (cn + 127) & ~127;
        transpose_k<<<dim3(npad / 64, 16), 256, 0, stream>>>(outW + c0, WtL, cn, VV, NN);
        mgemm_k<3><<<dim3(npad / 128, 8), 256, 0, stream>>>(h, WtL, out, outb, NN, VV, c0, VV, inv32, 0.f);
    }
}

// Round 4
// 2497.260 us; speedup vs baseline: 4.1818x; 1.5563x over previous
//
#include <hip/hip_runtime.h>
#include <hip/hip_bf16.h>

// Model constants
#define TT 512
#define NN 1024
#define NH 16
#define HD 64
#define NL 12
#define VV 50257

typedef unsigned short u16;
typedef short bf16x8 __attribute__((ext_vector_type(8)));
typedef float f32x4 __attribute__((ext_vector_type(4)));

__device__ __forceinline__ float gelu_f(float x) {
    float x3 = x * x * x;
    return 0.5f * x * (1.0f + tanhf(0.7978845608028654f * (x + 0.044715f * x3)));
}

// fp32 -> bf16 RNE (finite inputs only)
__device__ __forceinline__ u16 f2b(float f) {
    unsigned int u = __float_as_uint(f);
    return (u16)((u + 0x7FFFu + ((u >> 16) & 1u)) >> 16);
}

// async global->LDS, 16B per lane; LDS dest is wave-uniform base + lane*16
__device__ __forceinline__ void gload16(const void* g, void* l) {
    __builtin_amdgcn_global_load_lds(
        (const __attribute__((address_space(1))) unsigned int*)g,
        (__attribute__((address_space(3))) unsigned int*)l,
        16, 0, 0);
}

// x[row,:] = 1024*emb[tok[row],:] + 32*pos[t,:]
__global__ __launch_bounds__(256) void embed_k(const int* __restrict__ tok,
        const float* __restrict__ emb, const float* __restrict__ pos,
        float* __restrict__ x) {
    int row = blockIdx.x;
    int t = row & (TT - 1);
    int tk = tok[row];
    int c = threadIdx.x * 4;
    float4 e = *reinterpret_cast<const float4*>(emb + (size_t)tk * NN + c);
    float4 p = *reinterpret_cast<const float4*>(pos + (size_t)t * NN + c);
    float4 o;
    o.x = 1024.f * e.x + 32.f * p.x;
    o.y = 1024.f * e.y + 32.f * p.y;
    o.z = 1024.f * e.z + 32.f * p.z;
    o.w = 1024.f * e.w + 32.f * p.w;
    *reinterpret_cast<float4*>(x + (size_t)row * NN + c) = o;
}

// Row LayerNorm over N=1024 (+ optional gelu), bf16 output
template<int ACT>
__global__ __launch_bounds__(256) void ln_k(const float* __restrict__ in,
        u16* __restrict__ out, const float* __restrict__ sc, const float* __restrict__ bi) {
    int row = blockIdx.x;
    const float* r = in + (size_t)row * NN;
    int tid = threadIdx.x;
    float v[4]; float s1 = 0.f, s2 = 0.f;
    #pragma unroll
    for (int i = 0; i < 4; ++i) { v[i] = r[tid + i * 256]; s1 += v[i]; s2 += v[i] * v[i]; }
    #pragma unroll
    for (int off = 32; off > 0; off >>= 1) { s1 += __shfl_xor(s1, off); s2 += __shfl_xor(s2, off); }
    __shared__ float red[8];
    __shared__ float st[2];
    int wid = tid >> 6;
    if ((tid & 63) == 0) { red[wid] = s1; red[4 + wid] = s2; }
    __syncthreads();
    if (tid == 0) {
        float a = red[0] + red[1] + red[2] + red[3];
        float b = red[4] + red[5] + red[6] + red[7];
        float mu = a * (1.f / NN);
        float var = b * (1.f / NN) - mu * mu;
        st[0] = mu; st[1] = rsqrtf(var + 1e-6f);
    }
    __syncthreads();
    float mu = st[0], rs = st[1];
    u16* o = out + (size_t)row * NN;
    #pragma unroll
    for (int i = 0; i < 4; ++i) {
        int c = tid + i * 256;
        float y = (v[i] - mu) * rs * sc[c] + bi[c];
        if (ACT) y = gelu_f(y);
        o[c] = f2b(y);
    }
}

// qk buffer [B*T, 2048] -> per-head LN -> qh/kh bf16 [bh][t][64]
__global__ __launch_bounds__(256) void headln_k(const float* __restrict__ qk,
        const float* __restrict__ qs, const float* __restrict__ qb,
        const float* __restrict__ ks, const float* __restrict__ kb,
        u16* __restrict__ qh, u16* __restrict__ kh) {
    int u = blockIdx.x * 4 + (threadIdx.x >> 6);
    int lane = threadIdx.x & 63;
    int h = u & 15;
    int s = (u >> 4) & 1;
    int t = (u >> 5) & (TT - 1);
    int b = u >> 14;
    float x = qk[(size_t)(b * TT + t) * 2048 + h * 128 + s * 64 + lane];
    float s1 = x, s2 = x * x;
    #pragma unroll
    for (int off = 32; off > 0; off >>= 1) { s1 += __shfl_xor(s1, off); s2 += __shfl_xor(s2, off); }
    float mu = s1 * (1.f / 64.f);
    float var = s2 * (1.f / 64.f) - mu * mu;
    float rs = rsqrtf(var + 1e-6f);
    const float* scp = s ? ks : qs;
    const float* bip = s ? kb : qb;
    float y = (x - mu) * rs * scp[lane] + bip[lane];
    u16* dst = s ? kh : qh;
    dst[((size_t)(b * NH + h) * TT + t) * HD + lane] = f2b(y);
}

// Packed per-layer weight transpose: 5 fp32 [1024][Ncols] -> bf16 [Ncols][1024]
// z=0: qkW (2048 cols, dst 0); z=1..4: vW,oW,W1,W2 (1024 cols each)
__global__ __launch_bounds__(256) void transpose5_k(const float* __restrict__ qkW,
        const float* __restrict__ vW, const float* __restrict__ oW,
        const float* __restrict__ W1, const float* __restrict__ W2,
        u16* __restrict__ Wt) {
    int z = blockIdx.z;
    const float* W; int Ncols; size_t doff;
    switch (z) {
      case 0:  W = qkW; Ncols = 2048; doff = 0; break;
      case 1:  W = vW;  Ncols = 1024; doff = (size_t)2048 * 1024; break;
      case 2:  W = oW;  Ncols = 1024; doff = (size_t)3072 * 1024; break;
      case 3:  W = W1;  Ncols = 1024; doff = (size_t)4096 * 1024; break;
      default: W = W2;  Ncols = 1024; doff = (size_t)5120 * 1024; break;
    }
    int n0 = blockIdx.x * 64;
    if (n0 >= Ncols) return;
    int k0 = blockIdx.y * 64;
    u16* dst = Wt + doff;
    __shared__ float t[64][65];
    int tid = threadIdx.x;
    #pragma unroll
    for (int j = 0; j < 4; ++j) {
        int e = tid + j * 256;
        int kr = e >> 4, nc = (e & 15) * 4;
        float4 v = *reinterpret_cast<const float4*>(W + (size_t)(k0 + kr) * Ncols + n0 + nc);
        t[kr][nc + 0] = v.x; t[kr][nc + 1] = v.y; t[kr][nc + 2] = v.z; t[kr][nc + 3] = v.w;
    }
    __syncthreads();
    #pragma unroll
    for (int j = 0; j < 4; ++j) {
        int e = tid + j * 256;
        int nr = e >> 4, kc = (e & 15) * 4;
        ushort4 o;
        o.x = f2b(t[kc + 0][nr]);
        o.y = f2b(t[kc + 1][nr]);
        o.z = f2b(t[kc + 2][nr]);
        o.w = f2b(t[kc + 3][nr]);
        *reinterpret_cast<ushort4*>(dst + (size_t)(n0 + nr) * 1024 + k0 + kc) = o;
    }
}

// Guarded single transpose (logits chunks): fp32 [K][Ncols] ld=ldW -> bf16 [Npad][K]
__global__ __launch_bounds__(256) void transpose_k(const float* __restrict__ W,
        u16* __restrict__ Wt, int Ncols, int ldW, int K) {
    __shared__ float t[64][65];
    int n0 = blockIdx.x * 64, k0 = blockIdx.y * 64;
    int tid = threadIdx.x;
    #pragma unroll
    for (int j = 0; j < 4; ++j) {
        int e = tid + j * 256;
        int kr = e >> 4, nc = (e & 15) * 4;
        int n = n0 + nc;
        float4 v = {0.f, 0.f, 0.f, 0.f};
        if (n + 3 < Ncols) {
            v = *reinterpret_cast<const float4*>(W + (size_t)(k0 + kr) * ldW + n);
        } else {
            if (n + 0 < Ncols) v.x = W[(size_t)(k0 + kr) * ldW + n + 0];
            if (n + 1 < Ncols) v.y = W[(size_t)(k0 + kr) * ldW + n + 1];
            if (n + 2 < Ncols) v.z = W[(size_t)(k0 + kr) * ldW + n + 2];
        }
        t[kr][nc + 0] = v.x; t[kr][nc + 1] = v.y; t[kr][nc + 2] = v.z; t[kr][nc + 3] = v.w;
    }
    __syncthreads();
    #pragma unroll
    for (int j = 0; j < 4; ++j) {
        int e = tid + j * 256;
        int nr = e >> 4, kc = (e & 15) * 4;
        ushort4 o;
        o.x = f2b(t[kc + 0][nr]);
        o.y = f2b(t[kc + 1][nr]);
        o.z = f2b(t[kc + 2][nr]);
        o.w = f2b(t[kc + 3][nr]);
        *reinterpret_cast<ushort4*>(Wt + (size_t)(n0 + nr) * K + k0 + kc) = o;
    }
}

// swizzled LDS fragment read: row r, logical 16B chunk c
__device__ __forceinline__ bf16x8 ldsfrag(const u16* base, int r, int c) {
    int off = r * 64 + ((c ^ (r & 7)) << 3);
    return *reinterpret_cast<const bf16x8*>(base + off);
}

// MFMA GEMM: C = epilogue(A[M][K]bf16 @ Bt[N][K]bf16^T), 128x128 tile, BK=64.
// EPI 0: fp32 C = acc*scale
// EPI 1: fp32 C = C + rbeta*(acc*scale)   (residual in place)
// EPI 2: bf16 C = gelu(acc*scale)
// EPI 3: fp32 C[row*ldC + coff+n] = (acc + bias[coff+n])*scale, guarded coff+n<cmax
// EPI 4: bf16 V^T store: vt[bh][d][t] = acc*scale  (rows=b*512+t, cols=h*64+d)
template<int EPI>
__global__ __launch_bounds__(256) void mgemm_k(const u16* __restrict__ A,
        const u16* __restrict__ Bt, void* __restrict__ C,
        const float* __restrict__ bias, int K, int ldC, int coff, int cmax,
        float scale, float rbeta) {
    __shared__ __align__(16) u16 As[128 * 64];
    __shared__ __align__(16) u16 Bs[128 * 64];
    int tid = threadIdx.x;
    int lam = tid & 63;
    int w = tid >> 6;
    int m0 = blockIdx.y * 128, n0 = blockIdx.x * 128;
    int lr = lam >> 3;              // row-in-8 within a 1KB issue
    int lc = (lam & 7) ^ lr;        // inverse-swizzled logical chunk for this lane
    const u16* Abase = A + (size_t)m0 * K;
    const u16* Bbase = Bt + (size_t)n0 * K;
    f32x4 acc[4][4];
    #pragma unroll
    for (int i = 0; i < 4; ++i)
        #pragma unroll
        for (int j = 0; j < 4; ++j) acc[i][j] = (f32x4)0.0f;
    int wr = (w >> 1) * 64, wc = (w & 1) * 64;
    int fr = lam & 15, fg = lam >> 4;       // fragment row, k-group
    for (int k0 = 0; k0 < K; k0 += 64) {
        #pragma unroll
        for (int i = 0; i < 4; ++i) {
            int q = w * 4 + i;              // 16 issues cover 128 rows (8 rows each)
            int r = q * 8 + lr;
            gload16(Abase + (size_t)r * K + k0 + lc * 8, (char*)As + q * 1024);
            gload16(Bbase + (size_t)r * K + k0 + lc * 8, (char*)Bs + q * 1024);
        }
        __syncthreads();
        #pragma unroll
        for (int s = 0; s < 2; ++s) {       // two k=32 slices
            bf16x8 af[4], bfv[4];
            #pragma unroll
            for (int m = 0; m < 4; ++m) af[m] = ldsfrag(As, wr + m * 16 + fr, s * 4 + fg);
            #pragma unroll
            for (int n = 0; n < 4; ++n) bfv[n] = ldsfrag(Bs, wc + n * 16 + fr, s * 4 + fg);
            #pragma unroll
            for (int m = 0; m < 4; ++m)
                #pragma unroll
                for (int n = 0; n < 4; ++n)
                    acc[m][n] = __builtin_amdgcn_mfma_f32_16x16x32_bf16(af[m], bfv[n], acc[m][n], 0, 0, 0);
        }
        __syncthreads();
    }
    // C/D layout: col = lane&15, row = (lane>>4)*4 + reg
    if (EPI == 4) {
        #pragma unroll
        for (int m = 0; m < 4; ++m) {
            int mrow = m0 + wr + m * 16 + 4 * fg;   // 4 consecutive t
            int bb = mrow >> 9, tr = mrow & (TT - 1);
            #pragma unroll
            for (int n = 0; n < 4; ++n) {
                int ncol = n0 + wc + n * 16 + fr;
                int hh = ncol >> 6, dd = ncol & 63;
                ushort4 o4;
                o4.x = f2b(acc[m][n][0] * scale);
                o4.y = f2b(acc[m][n][1] * scale);
                o4.z = f2b(acc[m][n][2] * scale);
                o4.w = f2b(acc[m][n][3] * scale);
                *reinterpret_cast<ushort4*>((u16*)C +
                    (((size_t)(bb * NH + hh) * HD + dd) * TT + tr)) = o4;
            }
        }
        return;
    }
    #pragma unroll
    for (int m = 0; m < 4; ++m) {
        #pragma unroll
        for (int n = 0; n < 4; ++n) {
            int ncol = n0 + wc + n * 16 + fr;
            int mrow = m0 + wr + m * 16 + 4 * fg;
            #pragma unroll
            for (int reg = 0; reg < 4; ++reg) {
                int row = mrow + reg;
                float v = acc[m][n][reg];
                if (EPI == 0) {
                    ((float*)C)[(size_t)row * ldC + ncol] = v * scale;
                } else if (EPI == 1) {
                    float* p = (float*)C + (size_t)row * ldC + ncol;
                    *p = *p + rbeta * (v * scale);
                } else if (EPI == 2) {
                    ((u16*)C)[(size_t)row * ldC + ncol] = f2b(gelu_f(v * scale));
                } else {
                    int gc = coff + ncol;
                    if (gc < cmax)
                        ((float*)C)[(size_t)row * ldC + gc] = (v + bias[gc]) * scale;
                }
            }
        }
    }
}

// Fused flash attention: per (qt, bh) block, 4 waves x 16 q-rows.
// qh/kh bf16 [bh][t][64], vt bf16 [bh][d][t], ob bf16 [b][t][h*64+d].
// Unnormalized softmax (no max-sub, faithful to ref), online rowsum.
__global__ __launch_bounds__(256) void attn_k(const u16* __restrict__ qh,
        const u16* __restrict__ kh, const u16* __restrict__ vt,
        u16* __restrict__ ob) {
    int qt = blockIdx.x, bh = blockIdx.y;
    int b = bh >> 4, hh = bh & 15;
    int tid = threadIdx.x;
    int w = tid >> 6, lam = tid & 63;
    int fr = lam & 15, fg = lam >> 4;
    __shared__ __align__(16) u16 ps[4][16 * 64];   // per-wave P tile, XOR-swizzled
    u16* pw = ps[w];
    const u16* qbase = qh + ((size_t)bh * TT + qt * 64 + w * 16) * HD;
    bf16x8 af0 = *reinterpret_cast<const bf16x8*>(qbase + (size_t)fr * HD + fg * 8);
    bf16x8 af1 = *reinterpret_cast<const bf16x8*>(qbase + (size_t)fr * HD + 32 + fg * 8);
    f32x4 oacc[4];
    #pragma unroll
    for (int n = 0; n < 4; ++n) oacc[n] = (f32x4)0.0f;
    float rsum[4] = {0.f, 0.f, 0.f, 0.f};
    const u16* vbh = vt + (size_t)bh * HD * TT;
    for (int kt = 0; kt <= qt; ++kt) {
        const u16* kbase = kh + ((size_t)bh * TT + kt * 64) * HD;
        bool diag = (kt == qt);
        #pragma unroll
        for (int n = 0; n < 4; ++n) {
            bf16x8 b0 = *reinterpret_cast<const bf16x8*>(kbase + (size_t)(n * 16 + fr) * HD + fg * 8);
            bf16x8 b1 = *reinterpret_cast<const bf16x8*>(kbase + (size_t)(n * 16 + fr) * HD + 32 + fg * 8);
            f32x4 s = (f32x4)0.0f;
            s = __builtin_amdgcn_mfma_f32_16x16x32_bf16(af0, b0, s, 0, 0, 0);
            s = __builtin_amdgcn_mfma_f32_16x16x32_bf16(af1, b1, s, 0, 0, 0);
            // exp + causal mask + write P to LDS (C-layout -> A-layout via LDS)
            #pragma unroll
            for (int reg = 0; reg < 4; ++reg) {
                int row = fg * 4 + reg;            // q-local (this wave)
                int col = n * 16 + fr;             // k-local (0..63)
                float p = 0.f;
                if (!diag || col <= (w * 16 + row)) p = __expf(s[reg] * (1.f / 64.f));
                rsum[reg] += p;
                int chunk = col >> 3;
                int off = row * 128 + (((chunk ^ (row & 7)) << 4) | ((col & 7) << 1));
                *reinterpret_cast<u16*>((char*)pw + off) = f2b(p);
            }
        }
        // read P as A-frags (row = fr, k-chunk = ks*4+fg)
        bf16x8 pa0, pa1;
        {
            int c0 = 0 * 4 + fg, c1 = 1 * 4 + fg;
            pa0 = *reinterpret_cast<const bf16x8*>((char*)pw + fr * 128 + ((c0 ^ (fr & 7)) << 4));
            pa1 = *reinterpret_cast<const bf16x8*>((char*)pw + fr * 128 + ((c1 ^ (fr & 7)) << 4));
        }
        // PV: B-frag from vt[bh][d][t] (t contiguous)
        #pragma unroll
        for (int n = 0; n < 4; ++n) {
            const u16* vb = vbh + (size_t)(n * 16 + fr) * TT + kt * 64;
            bf16x8 v0 = *reinterpret_cast<const bf16x8*>(vb + fg * 8);
            bf16x8 v1 = *reinterpret_cast<const bf16x8*>(vb + 32 + fg * 8);
            oacc[n] = __builtin_amdgcn_mfma_f32_16x16x32_bf16(pa0, v0, oacc[n], 0, 0, 0);
            oacc[n] = __builtin_amdgcn_mfma_f32_16x16x32_bf16(pa1, v1, oacc[n], 0, 0, 0);
        }
    }
    // finalize rowsum across the 16 lanes of each col-group (lam bits 0..3)
    #pragma unroll
    for (int reg = 0; reg < 4; ++reg) {
        float r = rsum[reg];
        r += __shfl_xor(r, 1); r += __shfl_xor(r, 2);
        r += __shfl_xor(r, 4); r += __shfl_xor(r, 8);
        rsum[reg] = 1.f / r;
    }
    int tbase = b * TT + qt * 64 + w * 16 + fg * 4;
    #pragma unroll
    for (int n = 0; n < 4; ++n) {
        int dcol = hh * 64 + n * 16 + fr;
        #pragma unroll
        for (int reg = 0; reg < 4; ++reg)
            ob[(size_t)(tbase + reg) * NN + dcol] = f2b(oacc[n][reg] * rsum[reg]);
    }
}

extern "C" void kernel_launch(void* const* d_in, const int* in_sizes, int n_in,
                              void* d_out, int out_size, void* d_ws, size_t ws_size,
                              hipStream_t stream) {
    (void)in_sizes; (void)n_in; (void)out_size; (void)ws_size;
    const int*   tok  = (const int*)d_in[0];
    const float* emb  = (const float*)d_in[1];
    const float* pos  = (const float*)d_in[2];
    const float* ln1s = (const float*)d_in[3];
    const float* ln1b = (const float*)d_in[4];
    const float* qkW  = (const float*)d_in[5];
    const float* vW   = (const float*)d_in[6];
    const float* oW   = (const float*)d_in[7];
    const float* qns  = (const float*)d_in[8];
    const float* qnb  = (const float*)d_in[9];
    const float* kns  = (const float*)d_in[10];
    const float* knb  = (const float*)d_in[11];
    const float* ln2s = (const float*)d_in[12];
    const float* ln2b = (const float*)d_in[13];
    const float* W1   = (const float*)d_in[14];
    const float* W2   = (const float*)d_in[15];
    const float* lnfs = (const float*)d_in[16];
    const float* lnfb = (const float*)d_in[17];
    const float* outW = (const float*)d_in[18];
    const float* outb = (const float*)d_in[19];
    float* out = (float*)d_out;

    // ws layout: x f32 4MB | h bf16 2MB | qkbuf f32 8MB (mid bf16 reuse)
    //            qh,kh,vt,ob bf16 2MB each | Wt bf16 12MB | WtL bf16 16MB  => 50MB
    char* p = (char*)d_ws;
    float* x     = (float*)p;               p += (size_t)4  << 20;
    u16*   h     = (u16*)p;                 p += (size_t)2  << 20;
    float* qkbuf = (float*)p;               u16* mid = (u16*)qkbuf;
                                            p += (size_t)8  << 20;
    u16*   qh    = (u16*)p;                 p += (size_t)2  << 20;
    u16*   kh    = (u16*)p;                 p += (size_t)2  << 20;
    u16*   vt    = (u16*)p;                 p += (size_t)2  << 20;
    u16*   ob    = (u16*)p;                 p += (size_t)2  << 20;
    u16*   Wt    = (u16*)p;                 p += (size_t)12 << 20;
    u16*   WtL   = (u16*)p;

    const u16* WtQK = Wt;
    const u16* WtV  = Wt + (size_t)2048 * 1024;
    const u16* WtO  = Wt + (size_t)3072 * 1024;
    const u16* WtM1 = Wt + (size_t)4096 * 1024;
    const u16* WtM2 = Wt + (size_t)5120 * 1024;

    const float inv32 = 0.03125f;       // 1/sqrt(N)
    const float betaD = 1.f / 12.f;     // BETA / D

    embed_k<<<1024, 256, 0, stream>>>(tok, emb, pos, x);
    for (int l = 0; l < NL; ++l) {
        ln_k<1><<<1024, 256, 0, stream>>>(x, h, ln1s + l * NN, ln1b + l * NN);
        transpose5_k<<<dim3(32, 16, 5), 256, 0, stream>>>(
                qkW + (size_t)l * NN * 2048, vW + (size_t)l * NN * NN,
                oW + (size_t)l * NN * NN, W1 + (size_t)l * NN * NN,
                W2 + (size_t)l * NN * NN, Wt);
        // QK projection -> qkbuf fp32, then per-head LN -> bf16 qh/kh
        mgemm_k<0><<<dim3(16, 8), 256, 0, stream>>>(h, WtQK, qkbuf, nullptr, NN, 2048, 0, 0, inv32, 0.f);
        headln_k<<<8192, 256, 0, stream>>>(qkbuf, qns + l * HD, qnb + l * HD,
                kns + l * HD, knb + l * HD, qh, kh);
        // V projection -> vt (transpose-store)
        mgemm_k<4><<<dim3(8, 8), 256, 0, stream>>>(h, WtV, vt, nullptr, NN, NN, 0, 0, inv32, 0.f);
        // Fused attention
        attn_k<<<dim3(8, 32), 256, 0, stream>>>(qh, kh, vt, ob);
        // Output projection + residual
        mgemm_k<1><<<dim3(8, 8), 256, 0, stream>>>(ob, WtO, x, nullptr, NN, NN, 0, 0, inv32, betaD);
        // MLP
        ln_k<1><<<1024, 256, 0, stream>>>(x, h, ln2s + l * NN, ln2b + l * NN);
        mgemm_k<2><<<dim3(8, 8), 256, 0, stream>>>(h, WtM1, mid, nullptr, NN, NN, 0, 0, inv32, 0.f);
        mgemm_k<1><<<dim3(8, 8), 256, 0, stream>>>(mid, WtM2, x, nullptr, NN, NN, 0, 0, inv32, betaD);
    }
    ln_k<0><<<1024, 256, 0, stream>>>(x, h, lnfs, lnfb);
    // Logits, chunked over vocab
    for (int c0 = 0; c0 < VV; c0 += 8192) {
        int cn = VV - c0; if (cn > 8192) cn = 8192;
        int npad = (cn + 127) & ~127;
        transpose_k<<<dim3(npad / 64, 16), 256, 0, stream>>>(outW + c0, WtL, cn, VV, NN);
        mgemm_k<3><<<dim3(npad / 128, 8), 256, 0, stream>>>(h, WtL, out, outb, NN, VV, c0, VV, inv32, 0.f);
    }
}

// Round 5
// 1586.521 us; speedup vs baseline: 6.5823x; 1.5740x over previous
//
#include <hip/hip_runtime.h>
#include <hip/hip_bf16.h>

// Model constants
#define TT 512
#define NN 1024
#define NH 16
#define HD 64
#define NL 12
#define VV 50257

typedef unsigned short u16;
typedef short bf16x8 __attribute__((ext_vector_type(8)));
typedef float f32x4 __attribute__((ext_vector_type(4)));

__device__ __forceinline__ float gelu_f(float x) {
    float x3 = x * x * x;
    return 0.5f * x * (1.0f + tanhf(0.7978845608028654f * (x + 0.044715f * x3)));
}

// fp32 -> bf16 RNE (finite inputs only)
__device__ __forceinline__ u16 f2b(float f) {
    unsigned int u = __float_as_uint(f);
    return (u16)((u + 0x7FFFu + ((u >> 16) & 1u)) >> 16);
}

// async global->LDS, 16B per lane; LDS dest is wave-uniform base + lane*16
__device__ __forceinline__ void gload16(const void* g, void* l) {
    __builtin_amdgcn_global_load_lds(
        (const __attribute__((address_space(1))) unsigned int*)g,
        (__attribute__((address_space(3))) unsigned int*)l,
        16, 0, 0);
}

// x[row,:] = 1024*emb[tok[row],:] + 32*pos[t,:]
__global__ __launch_bounds__(256) void embed_k(const int* __restrict__ tok,
        const float* __restrict__ emb, const float* __restrict__ pos,
        float* __restrict__ x) {
    int row = blockIdx.x;
    int t = row & (TT - 1);
    int tk = tok[row];
    int c = threadIdx.x * 4;
    float4 e = *reinterpret_cast<const float4*>(emb + (size_t)tk * NN + c);
    float4 p = *reinterpret_cast<const float4*>(pos + (size_t)t * NN + c);
    float4 o;
    o.x = 1024.f * e.x + 32.f * p.x;
    o.y = 1024.f * e.y + 32.f * p.y;
    o.z = 1024.f * e.z + 32.f * p.z;
    o.w = 1024.f * e.w + 32.f * p.w;
    *reinterpret_cast<float4*>(x + (size_t)row * NN + c) = o;
}

// Row LayerNorm over N=1024 (+ optional gelu), bf16 output
template<int ACT>
__global__ __launch_bounds__(256) void ln_k(const float* __restrict__ in,
        u16* __restrict__ out, const float* __restrict__ sc, const float* __restrict__ bi) {
    int row = blockIdx.x;
    const float* r = in + (size_t)row * NN;
    int tid = threadIdx.x;
    float v[4]; float s1 = 0.f, s2 = 0.f;
    #pragma unroll
    for (int i = 0; i < 4; ++i) { v[i] = r[tid + i * 256]; s1 += v[i]; s2 += v[i] * v[i]; }
    #pragma unroll
    for (int off = 32; off > 0; off >>= 1) { s1 += __shfl_xor(s1, off); s2 += __shfl_xor(s2, off); }
    __shared__ float red[8];
    __shared__ float st[2];
    int wid = tid >> 6;
    if ((tid & 63) == 0) { red[wid] = s1; red[4 + wid] = s2; }
    __syncthreads();
    if (tid == 0) {
        float a = red[0] + red[1] + red[2] + red[3];
        float b = red[4] + red[5] + red[6] + red[7];
        float mu = a * (1.f / NN);
        float var = b * (1.f / NN) - mu * mu;
        st[0] = mu; st[1] = rsqrtf(var + 1e-6f);
    }
    __syncthreads();
    float mu = st[0], rs = st[1];
    u16* o = out + (size_t)row * NN;
    #pragma unroll
    for (int i = 0; i < 4; ++i) {
        int c = tid + i * 256;
        float y = (v[i] - mu) * rs * sc[c] + bi[c];
        if (ACT) y = gelu_f(y);
        o[c] = f2b(y);
    }
}

// Packed per-layer weight transpose: 5 fp32 [1024][Ncols] -> bf16 [Ncols][1024]
__global__ __launch_bounds__(256) void transpose5_k(const float* __restrict__ qkW,
        const float* __restrict__ vW, const float* __restrict__ oW,
        const float* __restrict__ W1, const float* __restrict__ W2,
        u16* __restrict__ Wt) {
    int z = blockIdx.z;
    const float* W; int Ncols; size_t doff;
    switch (z) {
      case 0:  W = qkW; Ncols = 2048; doff = 0; break;
      case 1:  W = vW;  Ncols = 1024; doff = (size_t)2048 * 1024; break;
      case 2:  W = oW;  Ncols = 1024; doff = (size_t)3072 * 1024; break;
      case 3:  W = W1;  Ncols = 1024; doff = (size_t)4096 * 1024; break;
      default: W = W2;  Ncols = 1024; doff = (size_t)5120 * 1024; break;
    }
    int n0 = blockIdx.x * 64;
    if (n0 >= Ncols) return;
    int k0 = blockIdx.y * 64;
    u16* dst = Wt + doff;
    __shared__ float t[64][65];
    int tid = threadIdx.x;
    #pragma unroll
    for (int j = 0; j < 4; ++j) {
        int e = tid + j * 256;
        int kr = e >> 4, nc = (e & 15) * 4;
        float4 v = *reinterpret_cast<const float4*>(W + (size_t)(k0 + kr) * Ncols + n0 + nc);
        t[kr][nc + 0] = v.x; t[kr][nc + 1] = v.y; t[kr][nc + 2] = v.z; t[kr][nc + 3] = v.w;
    }
    __syncthreads();
    #pragma unroll
    for (int j = 0; j < 4; ++j) {
        int e = tid + j * 256;
        int nr = e >> 4, kc = (e & 15) * 4;
        ushort4 o;
        o.x = f2b(t[kc + 0][nr]);
        o.y = f2b(t[kc + 1][nr]);
        o.z = f2b(t[kc + 2][nr]);
        o.w = f2b(t[kc + 3][nr]);
        *reinterpret_cast<ushort4*>(dst + (size_t)(n0 + nr) * 1024 + k0 + kc) = o;
    }
}

// Guarded single transpose (logits chunks): fp32 [K][Ncols] ld=ldW -> bf16 [Npad][K]
__global__ __launch_bounds__(256) void transpose_k(const float* __restrict__ W,
        u16* __restrict__ Wt, int Ncols, int ldW, int K) {
    __shared__ float t[64][65];
    int n0 = blockIdx.x * 64, k0 = blockIdx.y * 64;
    int tid = threadIdx.x;
    #pragma unroll
    for (int j = 0; j < 4; ++j) {
        int e = tid + j * 256;
        int kr = e >> 4, nc = (e & 15) * 4;
        int n = n0 + nc;
        float4 v = {0.f, 0.f, 0.f, 0.f};
        if (n + 3 < Ncols) {
            v = *reinterpret_cast<const float4*>(W + (size_t)(k0 + kr) * ldW + n);
        } else {
            if (n + 0 < Ncols) v.x = W[(size_t)(k0 + kr) * ldW + n + 0];
            if (n + 1 < Ncols) v.y = W[(size_t)(k0 + kr) * ldW + n + 1];
            if (n + 2 < Ncols) v.z = W[(size_t)(k0 + kr) * ldW + n + 2];
        }
        t[kr][nc + 0] = v.x; t[kr][nc + 1] = v.y; t[kr][nc + 2] = v.z; t[kr][nc + 3] = v.w;
    }
    __syncthreads();
    #pragma unroll
    for (int j = 0; j < 4; ++j) {
        int e = tid + j * 256;
        int nr = e >> 4, kc = (e & 15) * 4;
        ushort4 o;
        o.x = f2b(t[kc + 0][nr]);
        o.y = f2b(t[kc + 1][nr]);
        o.z = f2b(t[kc + 2][nr]);
        o.w = f2b(t[kc + 3][nr]);
        *reinterpret_cast<ushort4*>(Wt + (size_t)(n0 + nr) * K + k0 + kc) = o;
    }
}

// swizzled LDS fragment read: row r, logical 16B chunk c
__device__ __forceinline__ bf16x8 ldsfrag(const u16* base, int r, int c) {
    int off = r * 64 + ((c ^ (r & 7)) << 3);
    return *reinterpret_cast<const bf16x8*>(base + off);
}

// MFMA GEMM, TMxTN tile, BK=64, double-buffered 2-phase.
// Waves 2x2; per-wave output (TM/2)x(TN/2).
// EPI 1: fp32 C += rbeta*(acc*scale)  (residual in place)
// EPI 2: bf16 C = gelu(acc*scale)
// EPI 3: fp32 C[row*ldC+coff+n] = (acc+bias)*scale, guarded coff+n<cmax
// EPI 5: fused QKV epilogue: cols<2048 -> per-head LN -> qh(C2)/kh(C3) bf16 [bh][t][64];
//        cols>=2048 -> V^T store vt(C) bf16 [bh][d][t]
template<int TM, int TN, int EPI>
__global__ __launch_bounds__(256) void gemm_k(const u16* __restrict__ A,
        const u16* __restrict__ Bt, void* __restrict__ C,
        void* __restrict__ C2, void* __restrict__ C3,
        const float* __restrict__ bias,
        const float* __restrict__ qs, const float* __restrict__ qb,
        const float* __restrict__ ks, const float* __restrict__ kb,
        int K, int ldC, int coff, int cmax, float scale, float rbeta) {
    constexpr int MF = TM / 32, NF = TN / 32;     // frags per wave
    constexpr int IA = TM / 8, IB = TN / 8;       // 1KB staging issues
    __shared__ __align__(16) u16 As[2][TM * 64];
    __shared__ __align__(16) u16 Bs[2][TN * 64];
    int tid = threadIdx.x;
    int lam = tid & 63, w = tid >> 6;
    int m0 = blockIdx.y * TM, n0 = blockIdx.x * TN;
    int lr = lam >> 3;              // row-in-8 within a 1KB issue
    int lc = (lam & 7) ^ lr;        // inverse-swizzled logical chunk
    const u16* Abase = A + (size_t)m0 * K;
    const u16* Bbase = Bt + (size_t)n0 * K;
    int wr = (w >> 1) * (TM / 2), wc = (w & 1) * (TN / 2);
    int fr = lam & 15, fg = lam >> 4;
    f32x4 acc[MF][NF];
    #pragma unroll
    for (int i = 0; i < MF; ++i)
        #pragma unroll
        for (int j = 0; j < NF; ++j) acc[i][j] = (f32x4)0.0f;

    auto stage = [&](int buf, int k0) {
        #pragma unroll
        for (int i = 0; i < IA / 4; ++i) {
            int q = w * (IA / 4) + i;
            int r = q * 8 + lr;
            gload16(Abase + (size_t)r * K + k0 + lc * 8, (char*)As[buf] + q * 1024);
        }
        #pragma unroll
        for (int i = 0; i < IB / 4; ++i) {
            int q = w * (IB / 4) + i;
            int r = q * 8 + lr;
            gload16(Bbase + (size_t)r * K + k0 + lc * 8, (char*)Bs[buf] + q * 1024);
        }
    };
    auto compute = [&](int buf) {
        #pragma unroll
        for (int s = 0; s < 2; ++s) {
            bf16x8 af[MF], bfv[NF];
            #pragma unroll
            for (int m = 0; m < MF; ++m) af[m] = ldsfrag(As[buf], wr + m * 16 + fr, s * 4 + fg);
            #pragma unroll
            for (int n = 0; n < NF; ++n) bfv[n] = ldsfrag(Bs[buf], wc + n * 16 + fr, s * 4 + fg);
            #pragma unroll
            for (int m = 0; m < MF; ++m)
                #pragma unroll
                for (int n = 0; n < NF; ++n)
                    acc[m][n] = __builtin_amdgcn_mfma_f32_16x16x32_bf16(af[m], bfv[n], acc[m][n], 0, 0, 0);
        }
    };

    stage(0, 0);
    __syncthreads();
    int cur = 0;
    for (int k0 = 64; k0 < K; k0 += 64) {
        stage(cur ^ 1, k0);     // async loads in flight across compute
        compute(cur);
        __syncthreads();        // drains vmcnt(0) + barrier (2-phase)
        cur ^= 1;
    }
    compute(cur);

    // C/D layout: col = lane&15, row = (lane>>4)*4 + reg
    if (EPI == 5) {
        if (n0 < 2048) {
            int sq = wc >> 6;                    // 0 = q half, 1 = k half
            int head = n0 >> 7;
            const float* scp = sq ? ks : qs;
            const float* bip = sq ? kb : qb;
            u16* dst = (u16*)(sq ? C3 : C2);
            float scv[NF], biv[NF];
            #pragma unroll
            for (int n = 0; n < NF; ++n) { scv[n] = scp[n * 16 + fr]; biv[n] = bip[n * 16 + fr]; }
            #pragma unroll
            for (int m = 0; m < MF; ++m) {
                #pragma unroll
                for (int reg = 0; reg < 4; ++reg) {
                    float v[NF]; float s1 = 0.f, s2 = 0.f;
                    #pragma unroll
                    for (int n = 0; n < NF; ++n) {
                        v[n] = acc[m][n][reg] * scale;
                        s1 += v[n]; s2 += v[n] * v[n];
                    }
                    #pragma unroll
                    for (int off = 1; off < 16; off <<= 1) {
                        s1 += __shfl_xor(s1, off);
                        s2 += __shfl_xor(s2, off);
                    }
                    float mu = s1 * (1.f / 64.f);
                    float var = s2 * (1.f / 64.f) - mu * mu;
                    float rs = rsqrtf(var + 1e-6f);
                    int row = m0 + wr + m * 16 + 4 * fg + reg;
                    int bb = row >> 9, t = row & (TT - 1);
                    size_t base = ((size_t)(bb * NH + head) * TT + t) * HD;
                    #pragma unroll
                    for (int n = 0; n < NF; ++n)
                        dst[base + n * 16 + fr] = f2b((v[n] - mu) * rs * scv[n] + biv[n]);
                }
            }
        } else {
            #pragma unroll
            for (int m = 0; m < MF; ++m) {
                int row0 = m0 + wr + m * 16 + 4 * fg;
                int bb = row0 >> 9, t0 = row0 & (TT - 1);
                #pragma unroll
                for (int n = 0; n < NF; ++n) {
                    int colv = n0 - 2048 + wc + n * 16 + fr;
                    int hh = colv >> 6, dd = colv & 63;
                    ushort4 o4;
                    o4.x = f2b(acc[m][n][0] * scale);
                    o4.y = f2b(acc[m][n][1] * scale);
                    o4.z = f2b(acc[m][n][2] * scale);
                    o4.w = f2b(acc[m][n][3] * scale);
                    *reinterpret_cast<ushort4*>((u16*)C +
                        (((size_t)(bb * NH + hh) * HD + dd) * TT + t0)) = o4;
                }
            }
        }
        return;
    }
    #pragma unroll
    for (int m = 0; m < MF; ++m) {
        #pragma unroll
        for (int n = 0; n < NF; ++n) {
            int ncol = n0 + wc + n * 16 + fr;
            int mrow = m0 + wr + m * 16 + 4 * fg;
            #pragma unroll
            for (int reg = 0; reg < 4; ++reg) {
                int row = mrow + reg;
                float v = acc[m][n][reg];
                if (EPI == 1) {
                    float* p = (float*)C + (size_t)row * ldC + ncol;
                    *p = *p + rbeta * (v * scale);
                } else if (EPI == 2) {
                    ((u16*)C)[(size_t)row * ldC + ncol] = f2b(gelu_f(v * scale));
                } else {
                    int gc = coff + ncol;
                    if (gc < cmax)
                        ((float*)C)[(size_t)row * ldC + gc] = (v + bias[gc]) * scale;
                }
            }
        }
    }
}

// Fused flash attention: per (qt, bh) block, 4 waves x 16 q-rows.
// qh/kh bf16 [bh][t][64], vt bf16 [bh][d][t], ob bf16 [b][t][h*64+d].
// Unnormalized softmax (no max-sub, faithful to ref), online rowsum.
__global__ __launch_bounds__(256) void attn_k(const u16* __restrict__ qh,
        const u16* __restrict__ kh, const u16* __restrict__ vt,
        u16* __restrict__ ob) {
    int qt = blockIdx.x, bh = blockIdx.y;
    int b = bh >> 4, hh = bh & 15;
    int tid = threadIdx.x;
    int w = tid >> 6, lam = tid & 63;
    int fr = lam & 15, fg = lam >> 4;
    __shared__ __align__(16) u16 ps[4][16 * 64];   // per-wave P tile, XOR-swizzled
    u16* pw = ps[w];
    const u16* qbase = qh + ((size_t)bh * TT + qt * 64 + w * 16) * HD;
    bf16x8 af0 = *reinterpret_cast<const bf16x8*>(qbase + (size_t)fr * HD + fg * 8);
    bf16x8 af1 = *reinterpret_cast<const bf16x8*>(qbase + (size_t)fr * HD + 32 + fg * 8);
    f32x4 oacc[4];
    #pragma unroll
    for (int n = 0; n < 4; ++n) oacc[n] = (f32x4)0.0f;
    float rsum[4] = {0.f, 0.f, 0.f, 0.f};
    const u16* vbh = vt + (size_t)bh * HD * TT;
    for (int kt = 0; kt <= qt; ++kt) {
        const u16* kbase = kh + ((size_t)bh * TT + kt * 64) * HD;
        bool diag = (kt == qt);
        #pragma unroll
        for (int n = 0; n < 4; ++n) {
            bf16x8 b0 = *reinterpret_cast<const bf16x8*>(kbase + (size_t)(n * 16 + fr) * HD + fg * 8);
            bf16x8 b1 = *reinterpret_cast<const bf16x8*>(kbase + (size_t)(n * 16 + fr) * HD + 32 + fg * 8);
            f32x4 s = (f32x4)0.0f;
            s = __builtin_amdgcn_mfma_f32_16x16x32_bf16(af0, b0, s, 0, 0, 0);
            s = __builtin_amdgcn_mfma_f32_16x16x32_bf16(af1, b1, s, 0, 0, 0);
            #pragma unroll
            for (int reg = 0; reg < 4; ++reg) {
                int row = fg * 4 + reg;            // q-local (this wave)
                int col = n * 16 + fr;             // k-local (0..63)
                float p = 0.f;
                if (!diag || col <= (w * 16 + row)) p = __expf(s[reg] * (1.f / 64.f));
                rsum[reg] += p;
                int chunk = col >> 3;
                int off = row * 128 + (((chunk ^ (row & 7)) << 4) | ((col & 7) << 1));
                *reinterpret_cast<u16*>((char*)pw + off) = f2b(p);
            }
        }
        bf16x8 pa0, pa1;
        {
            int c0 = 0 * 4 + fg, c1 = 1 * 4 + fg;
            pa0 = *reinterpret_cast<const bf16x8*>((char*)pw + fr * 128 + ((c0 ^ (fr & 7)) << 4));
            pa1 = *reinterpret_cast<const bf16x8*>((char*)pw + fr * 128 + ((c1 ^ (fr & 7)) << 4));
        }
        #pragma unroll
        for (int n = 0; n < 4; ++n) {
            const u16* vb = vbh + (size_t)(n * 16 + fr) * TT + kt * 64;
            bf16x8 v0 = *reinterpret_cast<const bf16x8*>(vb + fg * 8);
            bf16x8 v1 = *reinterpret_cast<const bf16x8*>(vb + 32 + fg * 8);
            oacc[n] = __builtin_amdgcn_mfma_f32_16x16x32_bf16(pa0, v0, oacc[n], 0, 0, 0);
            oacc[n] = __builtin_amdgcn_mfma_f32_16x16x32_bf16(pa1, v1, oacc[n], 0, 0, 0);
        }
    }
    #pragma unroll
    for (int reg = 0; reg < 4; ++reg) {
        float r = rsum[reg];
        r += __shfl_xor(r, 1); r += __shfl_xor(r, 2);
        r += __shfl_xor(r, 4); r += __shfl_xor(r, 8);
        rsum[reg] = 1.f / r;
    }
    int tbase = b * TT + qt * 64 + w * 16 + fg * 4;
    #pragma unroll
    for (int n = 0; n < 4; ++n) {
        int dcol = hh * 64 + n * 16 + fr;
        #pragma unroll
        for (int reg = 0; reg < 4; ++reg)
            ob[(size_t)(tbase + reg) * NN + dcol] = f2b(oacc[n][reg] * rsum[reg]);
    }
}

extern "C" void kernel_launch(void* const* d_in, const int* in_sizes, int n_in,
                              void* d_out, int out_size, void* d_ws, size_t ws_size,
                              hipStream_t stream) {
    (void)in_sizes; (void)n_in; (void)out_size; (void)ws_size;
    const int*   tok  = (const int*)d_in[0];
    const float* emb  = (const float*)d_in[1];
    const float* pos  = (const float*)d_in[2];
    const float* ln1s = (const float*)d_in[3];
    const float* ln1b = (const float*)d_in[4];
    const float* qkW  = (const float*)d_in[5];
    const float* vW   = (const float*)d_in[6];
    const float* oW   = (const float*)d_in[7];
    const float* qns  = (const float*)d_in[8];
    const float* qnb  = (const float*)d_in[9];
    const float* kns  = (const float*)d_in[10];
    const float* knb  = (const float*)d_in[11];
    const float* ln2s = (const float*)d_in[12];
    const float* ln2b = (const float*)d_in[13];
    const float* W1   = (const float*)d_in[14];
    const float* W2   = (const float*)d_in[15];
    const float* lnfs = (const float*)d_in[16];
    const float* lnfb = (const float*)d_in[17];
    const float* outW = (const float*)d_in[18];
    const float* outb = (const float*)d_in[19];
    float* out = (float*)d_out;

    // ws layout: x f32 4MB | h bf16 2MB | mid bf16 2MB | qh,kh,vt,ob bf16 2MB each
    //            Wt bf16 12MB | WtL bf16 16MB  => 44MB
    char* p = (char*)d_ws;
    float* x   = (float*)p;   p += (size_t)4  << 20;
    u16*   h   = (u16*)p;     p += (size_t)2  << 20;
    u16*   mid = (u16*)p;     p += (size_t)2  << 20;
    u16*   qh  = (u16*)p;     p += (size_t)2  << 20;
    u16*   kh  = (u16*)p;     p += (size_t)2  << 20;
    u16*   vt  = (u16*)p;     p += (size_t)2  << 20;
    u16*   ob  = (u16*)p;     p += (size_t)2  << 20;
    u16*   Wt  = (u16*)p;     p += (size_t)12 << 20;
    u16*   WtL = (u16*)p;

    const u16* WtO  = Wt + (size_t)3072 * 1024;
    const u16* WtM1 = Wt + (size_t)4096 * 1024;
    const u16* WtM2 = Wt + (size_t)5120 * 1024;

    const float inv32 = 0.03125f;       // 1/sqrt(N)
    const float betaD = 1.f / 12.f;     // BETA / D

    embed_k<<<1024, 256, 0, stream>>>(tok, emb, pos, x);
    for (int l = 0; l < NL; ++l) {
        ln_k<1><<<1024, 256, 0, stream>>>(x, h, ln1s + l * NN, ln1b + l * NN);
        transpose5_k<<<dim3(32, 16, 5), 256, 0, stream>>>(
                qkW + (size_t)l * NN * 2048, vW + (size_t)l * NN * NN,
                oW + (size_t)l * NN * NN, W1 + (size_t)l * NN * NN,
                W2 + (size_t)l * NN * NN, Wt);
        // Fused QKV projection + per-head LN + V^T store (one launch, 384 blocks)
        gemm_k<64,128,5><<<dim3(24, 16), 256, 0, stream>>>(h, Wt, vt, qh, kh,
                nullptr, qns + l * HD, qnb + l * HD, kns + l * HD, knb + l * HD,
                NN, 0, 0, 0, inv32, 0.f);
        // Fused attention
        attn_k<<<dim3(8, 32), 256, 0, stream>>>(qh, kh, vt, ob);
        // Output projection + residual
        gemm_k<64,64,1><<<dim3(16, 16), 256, 0, stream>>>(ob, WtO, x, nullptr, nullptr,
                nullptr, nullptr, nullptr, nullptr, nullptr, NN, NN, 0, 0, inv32, betaD);
        // MLP
        ln_k<1><<<1024, 256, 0, stream>>>(x, h, ln2s + l * NN, ln2b + l * NN);
        gemm_k<64,64,2><<<dim3(16, 16), 256, 0, stream>>>(h, WtM1, mid, nullptr, nullptr,
                nullptr, nullptr, nullptr, nullptr, nullptr, NN, NN, 0, 0, inv32, 0.f);
        gemm_k<64,64,1><<<dim3(16, 16), 256, 0, stream>>>(mid, WtM2, x, nullptr, nullptr,
                nullptr, nullptr, nullptr, nullptr, nullptr, NN, NN, 0, 0, inv32, betaD);
    }
    ln_k<0><<<1024, 256, 0, stream>>>(x, h, lnfs, lnfb);
    // Logits, chunked over vocab
    for (int c0 = 0; c0 < VV; c0 += 8192) {
        int cn = VV - c0; if (cn > 8192) cn = 8192;
        int npad = (cn + 127) & ~127;
        transpose_k<<<dim3(npad / 64, 16), 256, 0, stream>>>(outW + c0, WtL, cn, VV, NN);
        gemm_k<128,128,3><<<dim3(npad / 128, 8), 256, 0, stream>>>(h, WtL, out, nullptr, nullptr,
                outb, nullptr, nullptr, nullptr, nullptr, NN, VV, c0, VV, inv32, 0.f);
    }
}